// Round 12
// baseline (187.576 us; speedup 1.0000x reference)
//
#include <hip/hip_runtime.h>
#include <cstdint>

#define DEVI __device__ __forceinline__

typedef unsigned short u16;
typedef __attribute__((ext_vector_type(4))) u16 u16x4;
typedef __attribute__((ext_vector_type(2))) unsigned int u32x2;
typedef __attribute__((ext_vector_type(2))) float f32x2;
typedef __attribute__((ext_vector_type(4))) float f32x4;
typedef __attribute__((ext_vector_type(8))) float f32x8;
typedef __attribute__((ext_vector_type(16))) float f32x16;
typedef __attribute__((ext_vector_type(8))) __bf16 bf16x8;

constexpr int kB = 8, kC = 384, kN = 2304, kNH = 6, kD = 64;
constexpr int kM = kB * kN;   // 18432
constexpr int k3C = 3 * kC;   // 1152
constexpr int kNT = kN / 64;  // 36 k-tiles (attn)
constexpr int kKS = kC / 32;  // 12 K-steps (gemm)
constexpr int kW1E = k3C * kC;  // 442368
constexpr int kW2E = kC * kC;   // 147456

DEVI float bf2f(u16 u) {
  union { unsigned int u; float f; } v; v.u = ((unsigned int)u) << 16; return v.f;
}
DEVI u16 f2bf(float f) {
  union { float f; unsigned int u; } v; v.f = f;
  return (u16)((v.u + 0x7fffu + ((v.u >> 16) & 1u)) >> 16);
}
DEVI void gload16(const void* g, void* l) {
  __builtin_amdgcn_global_load_lds(
      (__attribute__((address_space(1))) void*)const_cast<void*>(g),
      (__attribute__((address_space(3))) void*)l, 16, 0, 0);
}
DEVI bf16x8 ldg8(const u16* p) { return *reinterpret_cast<const bf16x8*>(p); }

DEVI float fexp2(float x) {
#if __has_builtin(__builtin_amdgcn_exp2f)
  return __builtin_amdgcn_exp2f(x);
#else
  return exp2f(x);
#endif
}

// pack two f32 -> one u32 of 2 bf16 (RNE), low word = first arg
DEVI unsigned cvtpk(float lo, float hi) {
  unsigned r;
  asm("v_cvt_pk_bf16_f32 %0, %1, %2" : "=v"(r) : "v"(lo), "v"(hi));
  return r;
}
// exchange halves across lane<32 / lane>=32
DEVI void plswap(unsigned& a, unsigned& b) {
#if __has_builtin(__builtin_amdgcn_permlane32_swap)
  auto rr = __builtin_amdgcn_permlane32_swap(a, b, false, false);
  a = rr[0]; b = rr[1];
#else
  unsigned ax = __shfl_xor(a, 32, 64), bx = __shfl_xor(b, 32, 64);
  int hi = (threadIdx.x & 63) >> 5;
  unsigned r0 = hi ? bx : a;
  unsigned r1 = hi ? b : ax;
  a = r0; b = r1;
#endif
}

// swizzled LDS read: tile row-major [rows][128 B], byte col XOR'd by row key
DEVI bf16x8 ldsw(const u16* base, int row, int cb) {
  return *reinterpret_cast<const bf16x8*>(
      (const char*)base + row * 128 + (cb ^ ((row & 7) << 4)));
}

// ---------------- LayerNorm + weight-cast fused ----------------
__global__ __launch_bounds__(256) void ln_cast_kernel(const float* __restrict__ x,
                                                      u16* __restrict__ tn,
                                                      const float* __restrict__ W1,
                                                      const float* __restrict__ W2,
                                                      u16* __restrict__ w1b,
                                                      u16* __restrict__ w2b) {
  if (blockIdx.x >= 288) {
    const int gid = (blockIdx.x - 288) * 256 + threadIdx.x;
    const int i4 = gid * 4;
    if (i4 < kW1E) {
      f32x4 v = *reinterpret_cast<const f32x4*>(&W1[i4]);
      u16x4 o;
#pragma unroll
      for (int r = 0; r < 4; ++r) o[r] = f2bf(v[r]);
      *reinterpret_cast<u16x4*>(&w1b[i4]) = o;
    } else if (i4 < kW1E + kW2E) {
      const int j = i4 - kW1E;
      f32x4 v = *reinterpret_cast<const f32x4*>(&W2[j]);
      u16x4 o;
#pragma unroll
      for (int r = 0; r < 4; ++r) o[r] = f2bf(v[r]);
      *reinterpret_cast<u16x4*>(&w2b[j]) = o;
    }
    return;
  }
  const int b = blockIdx.x & 7;
  const int n0 = (blockIdx.x >> 3) * 64;
  const int t = threadIdx.x;
  const int tni = t & 63, tc = t >> 6;
  const float* xb = x + (size_t)b * kC * kN;

  float sum = 0.f, ssq = 0.f;
  for (int c = tc; c < kC; c += 4) {
    float v = xb[(size_t)c * kN + n0 + tni];
    sum += v; ssq += v * v;
  }
  __shared__ float red[8][64];
  red[tc][tni] = sum; red[tc + 4][tni] = ssq;
  __syncthreads();
  __shared__ float s_mu[64], s_rs[64];
  if (t < 64) {
    float s = red[0][t] + red[1][t] + red[2][t] + red[3][t];
    float q = red[4][t] + red[5][t] + red[6][t] + red[7][t];
    float mu = s * (1.f / kC);
    float var = q * (1.f / kC) - mu * mu;
    s_mu[t] = mu; s_rs[t] = rsqrtf(var + 1e-5f);
  }
  __syncthreads();
  __shared__ float tile[64][65];
  for (int c0 = 0; c0 < kC; c0 += 64) {
#pragma unroll
    for (int kk = 0; kk < 16; ++kk) {
      int cl = tc * 16 + kk;
      tile[tni][cl] = xb[(size_t)(c0 + cl) * kN + n0 + tni];
    }
    __syncthreads();
#pragma unroll
    for (int kk = 0; kk < 16; ++kk) {
      int nl = tc * 16 + kk;
      float v = (tile[nl][tni] - s_mu[nl]) * s_rs[nl];
      tn[((size_t)b * kN + n0 + nl) * kC + c0 + tni] = f2bf(v);
    }
    __syncthreads();
  }
}

// ---- GEMM helpers: 64 B rows, slot key = (r>>1)&3 -> 8 rows cover 32 banks ----
DEVI int swzg(int r, int sl) { return (sl ^ ((r >> 1) & 3)) * 8; }  // u16 offset

// ================= 128x128 core (proj), 256 thr, BK=32, triple-buffer =================
#define GSTAGE(dstLds, gbase, kt)                                        \
  {                                                                      \
    _Pragma("unroll")                                                    \
    for (int c = 0; c < 2; ++c) {                                        \
      int i = c * 256 + t;                                               \
      int r = i >> 2, sl = i & 3;                                        \
      gload16((gbase) + (size_t)r * kC + (kt) + swzg(r, sl),             \
              (dstLds) + (c * 256 + (t & 192)) * 8);                     \
    }                                                                    \
  }

DEVI void gemm_core(const u16* __restrict__ A, const u16* __restrict__ Bm,
                    f32x4 acc[4][4], u16* lA, u16* lB) {
  const int t = threadIdx.x;
  const int lane = t & 63;
  const int w = t >> 6, wr = w >> 1, wc = w & 1;
  const int lr = lane & 15, lg = lane >> 4;

  GSTAGE(lA, A, 0)
  GSTAGE(lB, Bm, 0)

  int cur = 0;
#pragma unroll 3
  for (int s = 0; s < kKS; ++s) {
    const u16* cA = lA + cur * 4096;
    const u16* cB = lB + cur * 4096;
    const int nxt = (cur == 2) ? 0 : cur + 1;
    if (s + 1 < kKS) {
      GSTAGE(lA + nxt * 4096, A, (s + 1) * 32)
      GSTAGE(lB + nxt * 4096, Bm, (s + 1) * 32)
      asm volatile("s_waitcnt vmcnt(4)" ::: "memory");
    } else {
      asm volatile("s_waitcnt vmcnt(0)" ::: "memory");
    }
    __builtin_amdgcn_s_barrier();
    __builtin_amdgcn_sched_barrier(0);

    bf16x8 af[4], bfr[4];
#pragma unroll
    for (int f = 0; f < 4; ++f) {
      int row = wr * 64 + f * 16 + lr;
      af[f] = ldg8(&cA[row * 32 + swzg(row, lg)]);
    }
#pragma unroll
    for (int f = 0; f < 4; ++f) {
      int row = wc * 64 + f * 16 + lr;
      bfr[f] = ldg8(&cB[row * 32 + swzg(row, lg)]);
    }
    __builtin_amdgcn_s_setprio(1);
#pragma unroll
    for (int fm = 0; fm < 4; ++fm)
#pragma unroll
      for (int fn = 0; fn < 4; ++fn)
        acc[fm][fn] = __builtin_amdgcn_mfma_f32_16x16x32_bf16(af[fm], bfr[fn], acc[fm][fn], 0, 0, 0);
    __builtin_amdgcn_s_setprio(0);
    cur = nxt;
  }
}

// ================= 256x128 core (qkv), 512 thr / 8 waves, BK=32, triple-buffer =================
#define GSTAGE2A(dstLds, gbase, kt)                                      \
  {                                                                      \
    _Pragma("unroll")                                                    \
    for (int c = 0; c < 2; ++c) {                                        \
      int i = c * 512 + t;                                               \
      int r = i >> 2, sl = i & 3;                                        \
      gload16((gbase) + (size_t)r * kC + (kt) + swzg(r, sl),             \
              (dstLds) + (c * 512 + (t & 448)) * 8);                     \
    }                                                                    \
  }
#define GSTAGE2B(dstLds, gbase, kt)                                      \
  {                                                                      \
    int r = t >> 2, sl = t & 3;                                          \
    gload16((gbase) + (size_t)r * kC + (kt) + swzg(r, sl),               \
            (dstLds) + (t & 448) * 8);                                   \
  }

DEVI void gemm_core256(const u16* __restrict__ A, const u16* __restrict__ Bm,
                       f32x4 acc[4][4], u16* lA, u16* lB) {
  const int t = threadIdx.x;
  const int lane = t & 63;
  const int w = t >> 6, wr = w >> 1, wc = w & 1;
  const int lr = lane & 15, lg = lane >> 4;

  GSTAGE2A(lA, A, 0)
  GSTAGE2B(lB, Bm, 0)

  int cur = 0;
#pragma unroll 3
  for (int s = 0; s < kKS; ++s) {
    const u16* cA = lA + cur * 8192;
    const u16* cB = lB + cur * 4096;
    const int nxt = (cur == 2) ? 0 : cur + 1;
    if (s + 1 < kKS) {
      GSTAGE2A(lA + nxt * 8192, A, (s + 1) * 32)
      GSTAGE2B(lB + nxt * 4096, Bm, (s + 1) * 32)
      asm volatile("s_waitcnt vmcnt(3)" ::: "memory");
    } else {
      asm volatile("s_waitcnt vmcnt(0)" ::: "memory");
    }
    __builtin_amdgcn_s_barrier();
    __builtin_amdgcn_sched_barrier(0);

    bf16x8 af[4], bfr[4];
#pragma unroll
    for (int f = 0; f < 4; ++f) {
      int row = wr * 64 + f * 16 + lr;
      af[f] = ldg8(&cA[row * 32 + swzg(row, lg)]);
    }
#pragma unroll
    for (int f = 0; f < 4; ++f) {
      int row = wc * 64 + f * 16 + lr;
      bfr[f] = ldg8(&cB[row * 32 + swzg(row, lg)]);
    }
    __builtin_amdgcn_s_setprio(1);
#pragma unroll
    for (int fm = 0; fm < 4; ++fm)
#pragma unroll
      for (int fn = 0; fn < 4; ++fn)
        acc[fm][fn] = __builtin_amdgcn_mfma_f32_16x16x32_bf16(af[fm], bfr[fn], acc[fm][fn], 0, 0, 0);
    __builtin_amdgcn_s_setprio(0);
    cur = nxt;
  }
}

// ---------------- QKV GEMM: 256x128 tiles. q,k -> [B,h,N,d]; v -> TRANSPOSED [B,h,d,N] ----------------
__global__ __launch_bounds__(512) void qkv_kernel(const u16* __restrict__ tn, const u16* __restrict__ w1b,
                                                  const float* __restrict__ b1,
                                                  u16* __restrict__ q, u16* __restrict__ kbuf,
                                                  u16* __restrict__ vTout) {
  __shared__ u16 shmem[36864];  // 72KB: A bufs 3x8192, B bufs 3x4096; reused for transpose
  const int wg = blockIdx.x;
  const int xcd = wg & 7, idx = wg >> 3;
  const int m0 = (xcd * 9 + idx / 9) * 256;
  const int o0 = (idx % 9) * 128;
  f32x4 acc[4][4] = {};
  gemm_core256(tn + (size_t)m0 * kC, w1b + (size_t)o0 * kC, acc, shmem, shmem + 3 * 8192);

  const int t = threadIdx.x, lane = t & 63, w = t >> 6;
  const int wr = w >> 1, wc = w & 1, lr = lane & 15, lg = lane >> 4;
  const float kQScale = 0.125f * 1.44269504088896f;
  const int bb = xcd;
  const int nb0 = (idx / 9) * 256;
  const int ot = o0 >> 7;

  if (ot >= 6) {
    // ---- v: write transposed [b,h,d,n], 8B stores (n-fast)
#pragma unroll
    for (int fn = 0; fn < 4; ++fn) {
      int ol = o0 - 2 * kC + wc * 64 + fn * 16 + lr;
      float bias = b1[2 * kC + ol];
      int h = ol >> 6, dd = ol & 63;
#pragma unroll
      for (int fm = 0; fm < 4; ++fm) {
        int n4 = nb0 + wr * 64 + fm * 16 + lg * 4;
        u16x4 pk;
#pragma unroll
        for (int r = 0; r < 4; ++r) pk[r] = f2bf(acc[fm][fn][r] + bias);
        *reinterpret_cast<u16x4*>(&vTout[(((size_t)bb * kNH + h) * kD + dd) * kN + n4]) = pk;
      }
    }
  } else {
    // ---- q/k: LDS transpose -> coalesced 16B stores
    __syncthreads();
    const float scale = (ot < 3) ? kQScale : 1.0f;
#pragma unroll
    for (int fn = 0; fn < 4; ++fn) {
      int col = wc * 64 + fn * 16 + lr;
      float bias = b1[o0 + col];
#pragma unroll
      for (int fm = 0; fm < 4; ++fm)
#pragma unroll
        for (int r = 0; r < 4; ++r) {
          int row = wr * 64 + fm * 16 + lg * 4 + r;
          shmem[row * 132 + col] = f2bf((acc[fm][fn][r] + bias) * scale);
        }
    }
    __syncthreads();
    u16* outp = (ot < 3) ? q : kbuf;
    const int h0 = (o0 - (ot < 3 ? 0 : kC)) >> 6;
#pragma unroll
    for (int it = 0; it < 8; ++it) {
      int ci = it * 512 + t;
      int row = ci >> 4, ck = ci & 15;
      int c = ck * 8;
      int h = h0 + (c >> 6), dd = c & 63;
      *reinterpret_cast<bf16x8*>(&outp[(((size_t)bb * kNH + h) * kN + nb0 + row) * kD + dd]) =
          *reinterpret_cast<const bf16x8*>(&shmem[row * 132 + c]);
    }
  }
}

// ---------------- flash attention v12: dual-stream (64 q-rows/wave) ----------------
// 432 blocks = 8 XCD x (6 heads x 9 q-tiles), 256 thr / 4 waves. Each wave
// owns TWO independent 32-row streams: K/V frags read ONCE feed both streams'
// MFMAs, and stream B's MFMAs overlap stream A's softmax VALU (within-wave
// ILP). l-sum via packed vector adds (MFMA pipe is the busier one).
// 4 LDS buffers, depth-2 prefetch, counted vmcnt(8)/4/0.
#define PV_STEP2(SVa, SVb, OFF, KS)                                                   \
  {                                                                                   \
    bf16x8 vf0 = ldsw(vL, ql, (KS) * 32 + hi * 16);                                   \
    bf16x8 vf1 = ldsw(vL, 32 + ql, (KS) * 32 + hi * 16);                              \
    unsigned a0 = cvtpk(SVa[OFF + 0], SVa[OFF + 1]);                                  \
    unsigned a1 = cvtpk(SVa[OFF + 2], SVa[OFF + 3]);                                  \
    unsigned a2 = cvtpk(SVa[OFF + 4], SVa[OFF + 5]);                                  \
    unsigned a3 = cvtpk(SVa[OFF + 6], SVa[OFF + 7]);                                  \
    plswap(a0, a2); plswap(a1, a3);                                                   \
    union { unsigned wds[4]; bf16x8 v; } puA;                                         \
    puA.wds[0] = a0; puA.wds[1] = a1; puA.wds[2] = a2; puA.wds[3] = a3;               \
    o0a = __builtin_amdgcn_mfma_f32_32x32x16_bf16(vf0, puA.v, o0a, 0, 0, 0);          \
    o1a = __builtin_amdgcn_mfma_f32_32x32x16_bf16(vf1, puA.v, o1a, 0, 0, 0);          \
    unsigned b0 = cvtpk(SVb[OFF + 0], SVb[OFF + 1]);                                  \
    unsigned b1_ = cvtpk(SVb[OFF + 2], SVb[OFF + 3]);                                 \
    unsigned b2_ = cvtpk(SVb[OFF + 4], SVb[OFF + 5]);                                 \
    unsigned b3 = cvtpk(SVb[OFF + 6], SVb[OFF + 7]);                                  \
    plswap(b0, b2_); plswap(b1_, b3);                                                 \
    union { unsigned wds[4]; bf16x8 v; } puB;                                         \
    puB.wds[0] = b0; puB.wds[1] = b1_; puB.wds[2] = b2_; puB.wds[3] = b3;             \
    o0b = __builtin_amdgcn_mfma_f32_32x32x16_bf16(vf0, puB.v, o0b, 0, 0, 0);          \
    o1b = __builtin_amdgcn_mfma_f32_32x32x16_bf16(vf1, puB.v, o1b, 0, 0, 0);          \
  }

// stage one 64-row tile (row stride `gstride` bytes); 256 threads = 2 loads each
#define STAGE(dstLds, gbase, gstride)                                                 \
  {                                                                                   \
    _Pragma("unroll")                                                                 \
    for (int c = 0; c < 2; ++c) {                                                     \
      int i = c * 256 + t;                                                            \
      int r = i >> 3;                                                                 \
      int cb = ((i & 7) * 16) ^ ((r & 7) << 4);                                       \
      gload16((gbase) + (size_t)r * (gstride) + cb,                                   \
              (dstLds) + c * 2048 + (t & 192) * 8);                                   \
    }                                                                                 \
  }

__global__ __launch_bounds__(256) void attn_kernel(const u16* __restrict__ qg, const u16* __restrict__ kg,
                                                   const u16* __restrict__ vT, u16* __restrict__ obuf) {
  const int wg = blockIdx.x;
  const int xcd = wg & 7, idx = wg >> 3;
  const int bh = xcd * 6 + idx / 9;
  const int qt = idx % 9;
  const int b = bh / kNH, h = bh % kNH;
  const int t = threadIdx.x, lane = t & 63, w = t >> 6;
  const int q0w = qt * 256 + w * 64;       // wave owns 64 rows: A=+0, B=+32
  const int ql = lane & 31;
  const int hi = lane >> 5;
  const u16* qb  = qg + (size_t)bh * kN * kD;
  const char* kbB = (const char*)(kg + (size_t)bh * kN * kD);
  const char* vbT = (const char*)(vT + (size_t)bh * kD * kN);

  __shared__ u16 kLds[4 * 4096];
  __shared__ u16 vLds[4 * 4096];

  bf16x8 qfa[4], qfb[4];
#pragma unroll
  for (int ds = 0; ds < 4; ++ds) {
    qfa[ds] = ldg8(&qb[(size_t)(q0w + ql) * kD + ds * 16 + hi * 8]);
    qfb[ds] = ldg8(&qb[(size_t)(q0w + 32 + ql) * kD + ds * 16 + hi * 8]);
  }

  f32x16 o0a = {}, o1a = {}, o0b = {}, o1b = {};
  f32x16 lsumA = {}, lsumB = {};

  // depth-2 prologue: tiles 0 and 1
  STAGE(kLds, kbB, 128)
  STAGE(vLds, vbT, kN * 2)
  STAGE(kLds + 4096, kbB + (size_t)64 * 128, 128)
  STAGE(vLds + 4096, vbT + 128, kN * 2)

  int cur = 0;
  for (int ti = 0; ti < kNT; ++ti) {
    const u16* kL = kLds + cur * 4096;
    const u16* vL = vLds + cur * 4096;
    if (ti + 2 < kNT) {
      const int stg = (cur + 2) & 3;
      STAGE(kLds + stg * 4096, kbB + (size_t)(ti + 2) * 64 * 128, 128)
      STAGE(vLds + stg * 4096, vbT + (size_t)(ti + 2) * 128, kN * 2)
      asm volatile("s_waitcnt vmcnt(8)" ::: "memory");
    } else if (ti + 1 < kNT) {
      asm volatile("s_waitcnt vmcnt(4)" ::: "memory");
    } else {
      asm volatile("s_waitcnt vmcnt(0)" ::: "memory");
    }
    __builtin_amdgcn_s_barrier();
    __builtin_amdgcn_sched_barrier(0);

    // ---- S^T = K . Q^T for both streams; K frags read once
    f32x16 s0a = {}, s1a = {}, s0b = {}, s1b = {};
#pragma unroll
    for (int ds = 0; ds < 4; ++ds) {
      bf16x8 kf0 = ldsw(kL, ql, ds * 32 + hi * 16);
      bf16x8 kf1 = ldsw(kL, 32 + ql, ds * 32 + hi * 16);
      s0a = __builtin_amdgcn_mfma_f32_32x32x16_bf16(kf0, qfa[ds], s0a, 0, 0, 0);
      s1a = __builtin_amdgcn_mfma_f32_32x32x16_bf16(kf1, qfa[ds], s1a, 0, 0, 0);
      s0b = __builtin_amdgcn_mfma_f32_32x32x16_bf16(kf0, qfb[ds], s0b, 0, 0, 0);
      s1b = __builtin_amdgcn_mfma_f32_32x32x16_bf16(kf1, qfb[ds], s1b, 0, 0, 0);
    }

    // ---- softmax numerator in exp2 domain, no max subtraction
#pragma unroll
    for (int r = 0; r < 16; ++r) {
      s0a[r] = fexp2(s0a[r]);
      s1a[r] = fexp2(s1a[r]);
      s0b[r] = fexp2(s0b[r]);
      s1b[r] = fexp2(s1b[r]);
    }
    lsumA += s0a; lsumA += s1a;
    lsumB += s0b; lsumB += s1b;

    // ---- PV for both streams; V frags read once
    PV_STEP2(s0a, s0b, 0, 0)
    PV_STEP2(s0a, s0b, 8, 1)
    PV_STEP2(s1a, s1b, 0, 2)
    PV_STEP2(s1a, s1b, 8, 3)

    cur = (cur + 1) & 3;
  }

  // horizontal reduce of per-stream lsum + cross-half add
  f32x8 ra8 = __builtin_shufflevector(lsumA, lsumA, 0, 1, 2, 3, 4, 5, 6, 7) +
              __builtin_shufflevector(lsumA, lsumA, 8, 9, 10, 11, 12, 13, 14, 15);
  f32x4 ra4 = __builtin_shufflevector(ra8, ra8, 0, 1, 2, 3) +
              __builtin_shufflevector(ra8, ra8, 4, 5, 6, 7);
  f32x2 ra2 = __builtin_shufflevector(ra4, ra4, 0, 1) +
              __builtin_shufflevector(ra4, ra4, 2, 3);
  float la = ra2.x + ra2.y;
  la += __shfl_xor(la, 32, 64);
  f32x8 rb8 = __builtin_shufflevector(lsumB, lsumB, 0, 1, 2, 3, 4, 5, 6, 7) +
              __builtin_shufflevector(lsumB, lsumB, 8, 9, 10, 11, 12, 13, 14, 15);
  f32x4 rb4 = __builtin_shufflevector(rb8, rb8, 0, 1, 2, 3) +
              __builtin_shufflevector(rb8, rb8, 4, 5, 6, 7);
  f32x2 rb2 = __builtin_shufflevector(rb4, rb4, 0, 1) +
              __builtin_shufflevector(rb4, rb4, 2, 3);
  float lb = rb2.x + rb2.y;
  lb += __shfl_xor(lb, 32, 64);

  const float inva = 1.f / la;
  const float invb = 1.f / lb;
  {
    const size_t rowA = ((size_t)b * kN + q0w + ql) * kC + h * 64;
    const size_t rowB = ((size_t)b * kN + q0w + 32 + ql) * kC + h * 64;
#pragma unroll
    for (int g = 0; g < 4; ++g) {
      u32x2 pk;
      pk.x = cvtpk(o0a[g * 4 + 0] * inva, o0a[g * 4 + 1] * inva);
      pk.y = cvtpk(o0a[g * 4 + 2] * inva, o0a[g * 4 + 3] * inva);
      *reinterpret_cast<u32x2*>(&obuf[rowA + g * 8 + 4 * hi]) = pk;
    }
#pragma unroll
    for (int g = 0; g < 4; ++g) {
      u32x2 pk;
      pk.x = cvtpk(o1a[g * 4 + 0] * inva, o1a[g * 4 + 1] * inva);
      pk.y = cvtpk(o1a[g * 4 + 2] * inva, o1a[g * 4 + 3] * inva);
      *reinterpret_cast<u32x2*>(&obuf[rowA + 32 + g * 8 + 4 * hi]) = pk;
    }
#pragma unroll
    for (int g = 0; g < 4; ++g) {
      u32x2 pk;
      pk.x = cvtpk(o0b[g * 4 + 0] * invb, o0b[g * 4 + 1] * invb);
      pk.y = cvtpk(o0b[g * 4 + 2] * invb, o0b[g * 4 + 3] * invb);
      *reinterpret_cast<u32x2*>(&obuf[rowB + g * 8 + 4 * hi]) = pk;
    }
#pragma unroll
    for (int g = 0; g < 4; ++g) {
      u32x2 pk;
      pk.x = cvtpk(o1b[g * 4 + 0] * invb, o1b[g * 4 + 1] * invb);
      pk.y = cvtpk(o1b[g * 4 + 2] * invb, o1b[g * 4 + 3] * invb);
      *reinterpret_cast<u32x2*>(&obuf[rowB + 32 + g * 8 + 4 * hi]) = pk;
    }
  }
}

// ---------------- proj (transposed): out[b,c,n] = sum_k W2[c,k]*obuf[b,n,k] + b2[c] + tn[b,n,c] ----------------
__global__ __launch_bounds__(256) void proj_kernel(const u16* __restrict__ obuf, const u16* __restrict__ w2b,
                                                   const float* __restrict__ b2, const u16* __restrict__ tn,
                                                   float* __restrict__ out) {
  __shared__ u16 lAs[3 * 4096], lBs[3 * 4096];
  const int wg = blockIdx.x;
  const int xcd = wg & 7, idx = wg >> 3;
  const int bn = xcd * 18 + idx / 3;
  const int b = bn / 18;
  const int n0 = (bn % 18) * 128;
  const int c0 = (idx % 3) * 128;
  f32x4 acc[4][4] = {};
  gemm_core(w2b + (size_t)c0 * kC, obuf + ((size_t)b * kN + n0) * kC, acc, lAs, lBs);

  const int t = threadIdx.x, lane = t & 63, w = t >> 6;
  const int wr = w >> 1, wc = w & 1, lr = lane & 15, lg = lane >> 4;
#pragma unroll
  for (int fm = 0; fm < 4; ++fm)
#pragma unroll
    for (int fn = 0; fn < 4; ++fn) {
      int n = n0 + wc * 64 + fn * 16 + lr;
#pragma unroll
      for (int r = 0; r < 4; ++r) {
        int c = c0 + wr * 64 + fm * 16 + lg * 4 + r;
        float val = acc[fm][fn][r] + b2[c] + bf2f(tn[((size_t)b * kN + n) * kC + c]);
        out[((size_t)b * kC + c) * kN + n] = val;
      }
    }
}

extern "C" void kernel_launch(void* const* d_in, const int* in_sizes, int n_in,
                              void* d_out, int out_size, void* d_ws, size_t ws_size,
                              hipStream_t stream) {
  const float* x  = (const float*)d_in[0];
  const float* W1 = (const float*)d_in[1];
  const float* b1 = (const float*)d_in[2];
  const float* W2 = (const float*)d_in[3];
  const float* b2 = (const float*)d_in[4];
  float* out = (float*)d_out;

  const size_t nBNC = (size_t)kM * kC;  // 7,077,888 elements
  u16* tn  = (u16*)d_ws;
  u16* qb  = tn  + nBNC;
  u16* kb  = qb  + nBNC;
  u16* vb  = kb  + nBNC;   // free slot: obuf lives here
  u16* vT  = vb  + nBNC;
  u16* w1b = vT  + nBNC;
  u16* w2b = w1b + (size_t)k3C * kC;
  u16* obuf = vb;

  ln_cast_kernel<<<dim3(288 + 576), dim3(256), 0, stream>>>(x, tn, W1, W2, w1b, w2b);
  qkv_kernel<<<dim3(8 * 81), dim3(512), 0, stream>>>(tn, w1b, b1, qb, kb, vT);
  attn_kernel<<<dim3((kN / 256) * kB * kNH), dim3(256), 0, stream>>>(qb, kb, vT, obuf);
  proj_kernel<<<dim3((kN / 128) * (kC / 128) * kB), dim3(256), 0, stream>>>(obuf, w2b, b2, tn, out);
}

// Round 13
// 152.535 us; speedup vs baseline: 1.2297x; 1.2297x over previous
//
#include <hip/hip_runtime.h>
#include <cstdint>

#define DEVI __device__ __forceinline__

typedef unsigned short u16;
typedef __attribute__((ext_vector_type(4))) u16 u16x4;
typedef __attribute__((ext_vector_type(2))) unsigned int u32x2;
typedef __attribute__((ext_vector_type(2))) float f32x2;
typedef __attribute__((ext_vector_type(4))) float f32x4;
typedef __attribute__((ext_vector_type(8))) float f32x8;
typedef __attribute__((ext_vector_type(16))) float f32x16;
typedef __attribute__((ext_vector_type(8))) __bf16 bf16x8;

constexpr int kB = 8, kC = 384, kN = 2304, kNH = 6, kD = 64;
constexpr int kM = kB * kN;   // 18432
constexpr int k3C = 3 * kC;   // 1152
constexpr int kNT = kN / 64;  // 36 k-tiles (attn)
constexpr int kKS = kC / 32;  // 12 K-steps (gemm)
constexpr int kW1E = k3C * kC;  // 442368
constexpr int kW2E = kC * kC;   // 147456

DEVI float bf2f(u16 u) {
  union { unsigned int u; float f; } v; v.u = ((unsigned int)u) << 16; return v.f;
}
DEVI u16 f2bf(float f) {
  union { float f; unsigned int u; } v; v.f = f;
  return (u16)((v.u + 0x7fffu + ((v.u >> 16) & 1u)) >> 16);
}
DEVI void gload16(const void* g, void* l) {
  __builtin_amdgcn_global_load_lds(
      (__attribute__((address_space(1))) void*)const_cast<void*>(g),
      (__attribute__((address_space(3))) void*)l, 16, 0, 0);
}
DEVI bf16x8 ldg8(const u16* p) { return *reinterpret_cast<const bf16x8*>(p); }

DEVI float fexp2(float x) {
#if __has_builtin(__builtin_amdgcn_exp2f)
  return __builtin_amdgcn_exp2f(x);
#else
  return exp2f(x);
#endif
}

// pack two f32 -> one u32 of 2 bf16 (RNE), low word = first arg
DEVI unsigned cvtpk(float lo, float hi) {
  unsigned r;
  asm("v_cvt_pk_bf16_f32 %0, %1, %2" : "=v"(r) : "v"(lo), "v"(hi));
  return r;
}
// exchange halves across lane<32 / lane>=32
DEVI void plswap(unsigned& a, unsigned& b) {
#if __has_builtin(__builtin_amdgcn_permlane32_swap)
  auto rr = __builtin_amdgcn_permlane32_swap(a, b, false, false);
  a = rr[0]; b = rr[1];
#else
  unsigned ax = __shfl_xor(a, 32, 64), bx = __shfl_xor(b, 32, 64);
  int hi = (threadIdx.x & 63) >> 5;
  unsigned r0 = hi ? bx : a;
  unsigned r1 = hi ? b : ax;
  a = r0; b = r1;
#endif
}

// swizzled LDS read: tile row-major [rows][128 B], byte col XOR'd by row key
DEVI bf16x8 ldsw(const u16* base, int row, int cb) {
  return *reinterpret_cast<const bf16x8*>(
      (const char*)base + row * 128 + (cb ^ ((row & 7) << 4)));
}

// ---------------- LayerNorm + weight-cast fused ----------------
// blocks 0..575: LN over 32-row n-tiles (b = wg&7 -> batch b's tn lands on
// XCD b's L2). blocks 576..1151: cast W1/W2 to bf16, 4 elems/thread.
__global__ __launch_bounds__(256) void ln_cast_kernel(const float* __restrict__ x,
                                                      u16* __restrict__ tn,
                                                      const float* __restrict__ W1,
                                                      const float* __restrict__ W2,
                                                      u16* __restrict__ w1b,
                                                      u16* __restrict__ w2b) {
  if (blockIdx.x >= 576) {
    const int gid = (blockIdx.x - 576) * 256 + threadIdx.x;
    const int i4 = gid * 4;
    if (i4 < kW1E) {
      f32x4 v = *reinterpret_cast<const f32x4*>(&W1[i4]);
      u16x4 o;
#pragma unroll
      for (int r = 0; r < 4; ++r) o[r] = f2bf(v[r]);
      *reinterpret_cast<u16x4*>(&w1b[i4]) = o;
    } else if (i4 < kW1E + kW2E) {
      const int j = i4 - kW1E;
      f32x4 v = *reinterpret_cast<const f32x4*>(&W2[j]);
      u16x4 o;
#pragma unroll
      for (int r = 0; r < 4; ++r) o[r] = f2bf(v[r]);
      *reinterpret_cast<u16x4*>(&w2b[j]) = o;
    }
    return;
  }
  const int b = blockIdx.x & 7;
  const int n0 = (blockIdx.x >> 3) * 32;
  const int t = threadIdx.x;
  const int tni = t & 31, tc = t >> 5;  // tni: n in [0,32), tc: c-slice [0,8)
  const float* xb = x + (size_t)b * kC * kN;

  float sum = 0.f, ssq = 0.f;
  for (int c = tc; c < kC; c += 8) {
    float v = xb[(size_t)c * kN + n0 + tni];
    sum += v; ssq += v * v;
  }
  __shared__ float red[16][32];
  red[tc][tni] = sum; red[tc + 8][tni] = ssq;
  __syncthreads();
  __shared__ float s_mu[32], s_rs[32];
  if (t < 32) {
    float s = 0.f, q = 0.f;
#pragma unroll
    for (int j = 0; j < 8; ++j) { s += red[j][t]; q += red[j + 8][t]; }
    float mu = s * (1.f / kC);
    float var = q * (1.f / kC) - mu * mu;
    s_mu[t] = mu; s_rs[t] = rsqrtf(var + 1e-5f);
  }
  __syncthreads();
  __shared__ float tile[32][65];
  for (int c0 = 0; c0 < kC; c0 += 64) {
#pragma unroll
    for (int kk = 0; kk < 8; ++kk) {
      int cl = tc * 8 + kk;
      tile[tni][cl] = xb[(size_t)(c0 + cl) * kN + n0 + tni];
    }
    __syncthreads();
    const int tci = t & 63, trw = t >> 6;
#pragma unroll
    for (int kk = 0; kk < 8; ++kk) {
      int nl = trw * 8 + kk;
      float v = (tile[nl][tci] - s_mu[nl]) * s_rs[nl];
      tn[((size_t)b * kN + n0 + nl) * kC + c0 + tci] = f2bf(v);
    }
    __syncthreads();
  }
}

// ---- GEMM helpers: 64 B rows, slot key = (r>>1)&3 -> 8 rows cover 32 banks ----
DEVI int swzg(int r, int sl) { return (sl ^ ((r >> 1) & 3)) * 8; }  // u16 offset

// ================= 128x128 core (proj), 256 thr, BK=32, triple-buffer =================
#define GSTAGE(dstLds, gbase, kt)                                        \
  {                                                                      \
    _Pragma("unroll")                                                    \
    for (int c = 0; c < 2; ++c) {                                        \
      int i = c * 256 + t;                                               \
      int r = i >> 2, sl = i & 3;                                        \
      gload16((gbase) + (size_t)r * kC + (kt) + swzg(r, sl),             \
              (dstLds) + (c * 256 + (t & 192)) * 8);                     \
    }                                                                    \
  }

DEVI void gemm_core(const u16* __restrict__ A, const u16* __restrict__ Bm,
                    f32x4 acc[4][4], u16* lA, u16* lB) {
  const int t = threadIdx.x;
  const int lane = t & 63;
  const int w = t >> 6, wr = w >> 1, wc = w & 1;
  const int lr = lane & 15, lg = lane >> 4;

  GSTAGE(lA, A, 0)
  GSTAGE(lB, Bm, 0)

  int cur = 0;
#pragma unroll 3
  for (int s = 0; s < kKS; ++s) {
    const u16* cA = lA + cur * 4096;
    const u16* cB = lB + cur * 4096;
    const int nxt = (cur == 2) ? 0 : cur + 1;
    if (s + 1 < kKS) {
      GSTAGE(lA + nxt * 4096, A, (s + 1) * 32)
      GSTAGE(lB + nxt * 4096, Bm, (s + 1) * 32)
      asm volatile("s_waitcnt vmcnt(4)" ::: "memory");
    } else {
      asm volatile("s_waitcnt vmcnt(0)" ::: "memory");
    }
    __builtin_amdgcn_s_barrier();
    __builtin_amdgcn_sched_barrier(0);

    bf16x8 af[4], bfr[4];
#pragma unroll
    for (int f = 0; f < 4; ++f) {
      int row = wr * 64 + f * 16 + lr;
      af[f] = ldg8(&cA[row * 32 + swzg(row, lg)]);
    }
#pragma unroll
    for (int f = 0; f < 4; ++f) {
      int row = wc * 64 + f * 16 + lr;
      bfr[f] = ldg8(&cB[row * 32 + swzg(row, lg)]);
    }
    __builtin_amdgcn_s_setprio(1);
#pragma unroll
    for (int fm = 0; fm < 4; ++fm)
#pragma unroll
      for (int fn = 0; fn < 4; ++fn)
        acc[fm][fn] = __builtin_amdgcn_mfma_f32_16x16x32_bf16(af[fm], bfr[fn], acc[fm][fn], 0, 0, 0);
    __builtin_amdgcn_s_setprio(0);
    cur = nxt;
  }
}

// ================= 256x128 core (qkv), 512 thr / 8 waves, BK=32, triple-buffer =================
#define GSTAGE2A(dstLds, gbase, kt)                                      \
  {                                                                      \
    _Pragma("unroll")                                                    \
    for (int c = 0; c < 2; ++c) {                                        \
      int i = c * 512 + t;                                               \
      int r = i >> 2, sl = i & 3;                                        \
      gload16((gbase) + (size_t)r * kC + (kt) + swzg(r, sl),             \
              (dstLds) + (c * 512 + (t & 448)) * 8);                     \
    }                                                                    \
  }
#define GSTAGE2B(dstLds, gbase, kt)                                      \
  {                                                                      \
    int r = t >> 2, sl = t & 3;                                          \
    gload16((gbase) + (size_t)r * kC + (kt) + swzg(r, sl),               \
            (dstLds) + (t & 448) * 8);                                   \
  }

DEVI void gemm_core256(const u16* __restrict__ A, const u16* __restrict__ Bm,
                       f32x4 acc[4][4], u16* lA, u16* lB) {
  const int t = threadIdx.x;
  const int lane = t & 63;
  const int w = t >> 6, wr = w >> 1, wc = w & 1;
  const int lr = lane & 15, lg = lane >> 4;

  GSTAGE2A(lA, A, 0)
  GSTAGE2B(lB, Bm, 0)

  int cur = 0;
#pragma unroll 3
  for (int s = 0; s < kKS; ++s) {
    const u16* cA = lA + cur * 8192;
    const u16* cB = lB + cur * 4096;
    const int nxt = (cur == 2) ? 0 : cur + 1;
    if (s + 1 < kKS) {
      GSTAGE2A(lA + nxt * 8192, A, (s + 1) * 32)
      GSTAGE2B(lB + nxt * 4096, Bm, (s + 1) * 32)
      asm volatile("s_waitcnt vmcnt(3)" ::: "memory");
    } else {
      asm volatile("s_waitcnt vmcnt(0)" ::: "memory");
    }
    __builtin_amdgcn_s_barrier();
    __builtin_amdgcn_sched_barrier(0);

    bf16x8 af[4], bfr[4];
#pragma unroll
    for (int f = 0; f < 4; ++f) {
      int row = wr * 64 + f * 16 + lr;
      af[f] = ldg8(&cA[row * 32 + swzg(row, lg)]);
    }
#pragma unroll
    for (int f = 0; f < 4; ++f) {
      int row = wc * 64 + f * 16 + lr;
      bfr[f] = ldg8(&cB[row * 32 + swzg(row, lg)]);
    }
    __builtin_amdgcn_s_setprio(1);
#pragma unroll
    for (int fm = 0; fm < 4; ++fm)
#pragma unroll
      for (int fn = 0; fn < 4; ++fn)
        acc[fm][fn] = __builtin_amdgcn_mfma_f32_16x16x32_bf16(af[fm], bfr[fn], acc[fm][fn], 0, 0, 0);
    __builtin_amdgcn_s_setprio(0);
    cur = nxt;
  }
}

// ---------------- QKV GEMM: 256x128 tiles. q,k -> [B,h,N,d]; v -> TRANSPOSED [B,h,d,N] ----------------
__global__ __launch_bounds__(512) void qkv_kernel(const u16* __restrict__ tn, const u16* __restrict__ w1b,
                                                  const float* __restrict__ b1,
                                                  u16* __restrict__ q, u16* __restrict__ kbuf,
                                                  u16* __restrict__ vTout) {
  __shared__ u16 shmem[36864];  // 72KB: A bufs 3x8192, B bufs 3x4096; reused for transpose
  const int wg = blockIdx.x;
  const int xcd = wg & 7, idx = wg >> 3;
  const int m0 = (xcd * 9 + idx / 9) * 256;
  const int o0 = (idx % 9) * 128;
  f32x4 acc[4][4] = {};
  gemm_core256(tn + (size_t)m0 * kC, w1b + (size_t)o0 * kC, acc, shmem, shmem + 3 * 8192);

  const int t = threadIdx.x, lane = t & 63, w = t >> 6;
  const int wr = w >> 1, wc = w & 1, lr = lane & 15, lg = lane >> 4;
  const float kQScale = 0.125f * 1.44269504088896f;
  const int bb = xcd;
  const int nb0 = (idx / 9) * 256;
  const int ot = o0 >> 7;

  if (ot >= 6) {
    // ---- v: write transposed [b,h,d,n], 8B stores (n-fast)
#pragma unroll
    for (int fn = 0; fn < 4; ++fn) {
      int ol = o0 - 2 * kC + wc * 64 + fn * 16 + lr;
      float bias = b1[2 * kC + ol];
      int h = ol >> 6, dd = ol & 63;
#pragma unroll
      for (int fm = 0; fm < 4; ++fm) {
        int n4 = nb0 + wr * 64 + fm * 16 + lg * 4;
        u16x4 pk;
#pragma unroll
        for (int r = 0; r < 4; ++r) pk[r] = f2bf(acc[fm][fn][r] + bias);
        *reinterpret_cast<u16x4*>(&vTout[(((size_t)bb * kNH + h) * kD + dd) * kN + n4]) = pk;
      }
    }
  } else {
    // ---- q/k: LDS transpose -> coalesced 16B stores
    __syncthreads();
    const float scale = (ot < 3) ? kQScale : 1.0f;
#pragma unroll
    for (int fn = 0; fn < 4; ++fn) {
      int col = wc * 64 + fn * 16 + lr;
      float bias = b1[o0 + col];
#pragma unroll
      for (int fm = 0; fm < 4; ++fm)
#pragma unroll
        for (int r = 0; r < 4; ++r) {
          int row = wr * 64 + fm * 16 + lg * 4 + r;
          shmem[row * 132 + col] = f2bf((acc[fm][fn][r] + bias) * scale);
        }
    }
    __syncthreads();
    u16* outp = (ot < 3) ? q : kbuf;
    const int h0 = (o0 - (ot < 3 ? 0 : kC)) >> 6;
#pragma unroll
    for (int it = 0; it < 8; ++it) {
      int ci = it * 512 + t;
      int row = ci >> 4, ck = ci & 15;
      int c = ck * 8;
      int h = h0 + (c >> 6), dd = c & 63;
      *reinterpret_cast<bf16x8*>(&outp[(((size_t)bb * kNH + h) * kN + nb0 + row) * kD + dd]) =
          *reinterpret_cast<const bf16x8*>(&shmem[row * 132 + c]);
    }
  }
}

// ---------------- flash attention (r11-proven): 8 waves, depth-2 prefetch, 4 LDS buffers ----------------
// 432 blocks = 8 XCD x (6 heads x 9 q-tiles), 512 thr / 8 waves x 32 q-rows.
// Stage tile t+2 at iter t; counted s_waitcnt vmcnt(4)/(2)/(0) never drains
// mid-loop. exp2-domain softmax, no max tracking; l-sum via ones-row MFMA.
#define PV_STEP(SV, OFF, KS)                                                          \
  {                                                                                   \
    unsigned a0 = cvtpk(SV[OFF + 0], SV[OFF + 1]);                                    \
    unsigned a1 = cvtpk(SV[OFF + 2], SV[OFF + 3]);                                    \
    unsigned a2 = cvtpk(SV[OFF + 4], SV[OFF + 5]);                                    \
    unsigned a3 = cvtpk(SV[OFF + 6], SV[OFF + 7]);                                    \
    plswap(a0, a2); plswap(a1, a3);                                                   \
    union { unsigned wds[4]; bf16x8 v; } pu;                                          \
    pu.wds[0] = a0; pu.wds[1] = a1; pu.wds[2] = a2; pu.wds[3] = a3;                   \
    bf16x8 vf0 = ldsw(vL, ql, (KS) * 32 + hi * 16);                                   \
    bf16x8 vf1 = ldsw(vL, 32 + ql, (KS) * 32 + hi * 16);                              \
    o0 = __builtin_amdgcn_mfma_f32_32x32x16_bf16(vf0, pu.v, o0, 0, 0, 0);             \
    o1 = __builtin_amdgcn_mfma_f32_32x32x16_bf16(vf1, pu.v, o1, 0, 0, 0);             \
    o2 = __builtin_amdgcn_mfma_f32_32x32x16_bf16(onesf, pu.v, o2, 0, 0, 0);           \
  }

// stage one 64-row tile (row stride `gstride` bytes); 512 threads = 1 load each
#define STAGE(dstLds, gbase, gstride)                                                 \
  {                                                                                   \
    int r_ = t >> 3;                                                                  \
    int cb_ = ((t & 7) * 16) ^ ((r_ & 7) << 4);                                       \
    gload16((gbase) + (size_t)r_ * (gstride) + cb_,                                   \
            (dstLds) + (t & 448) * 8);                                                \
  }

__global__ __launch_bounds__(512) void attn_kernel(const u16* __restrict__ qg, const u16* __restrict__ kg,
                                                   const u16* __restrict__ vT, u16* __restrict__ obuf) {
  const int wg = blockIdx.x;
  const int xcd = wg & 7, idx = wg >> 3;
  const int bh = xcd * 6 + idx / 9;
  const int qt = idx % 9;
  const int b = bh / kNH, h = bh % kNH;
  const int t = threadIdx.x, lane = t & 63, w = t >> 6;
  const int q0w = qt * 256 + w * 32;
  const int ql = lane & 31;
  const int hi = lane >> 5;
  const u16* qb  = qg + (size_t)bh * kN * kD;
  const char* kbB = (const char*)(kg + (size_t)bh * kN * kD);
  const char* vbT = (const char*)(vT + (size_t)bh * kD * kN);

  __shared__ u16 kLds[4 * 4096];
  __shared__ u16 vLds[4 * 4096];

  // Q as B-fragment: Q[q0w+ql][ds*16 + hi*8 + j]
  bf16x8 qf[4];
#pragma unroll
  for (int ds = 0; ds < 4; ++ds)
    qf[ds] = ldg8(&qb[(size_t)(q0w + ql) * kD + ds * 16 + hi * 8]);

  bf16x8 onesf;
#pragma unroll
  for (int j = 0; j < 8; ++j) onesf[j] = (__bf16)1.0f;

  f32x16 o0 = {}, o1 = {}, o2 = {};

  // depth-2 prologue: tiles 0 and 1
  STAGE(kLds, kbB, 128)
  STAGE(vLds, vbT, kN * 2)
  STAGE(kLds + 4096, kbB + (size_t)64 * 128, 128)
  STAGE(vLds + 4096, vbT + 128, kN * 2)

  int cur = 0;
  for (int ti = 0; ti < kNT; ++ti) {
    const u16* kL = kLds + cur * 4096;
    const u16* vL = vLds + cur * 4096;
    if (ti + 2 < kNT) {
      const int stg = (cur + 2) & 3;
      const char* kNext = kbB + (size_t)(ti + 2) * 64 * 128;
      const char* vNext = vbT + (size_t)(ti + 2) * 128;
      STAGE(kLds + stg * 4096, kNext, 128)
      STAGE(vLds + stg * 4096, vNext, kN * 2)
      asm volatile("s_waitcnt vmcnt(4)" ::: "memory");
    } else if (ti + 1 < kNT) {
      asm volatile("s_waitcnt vmcnt(2)" ::: "memory");
    } else {
      asm volatile("s_waitcnt vmcnt(0)" ::: "memory");
    }
    __builtin_amdgcn_s_barrier();
    __builtin_amdgcn_sched_barrier(0);

    // ---- S^T[k][q] = K . Q^T : s0 = k-rows [0,32), s1 = [32,64) of tile
    f32x16 s0 = {}, s1 = {};
#pragma unroll
    for (int ds = 0; ds < 4; ++ds) {
      bf16x8 kf0 = ldsw(kL, ql, ds * 32 + hi * 16);
      bf16x8 kf1 = ldsw(kL, 32 + ql, ds * 32 + hi * 16);
      s0 = __builtin_amdgcn_mfma_f32_32x32x16_bf16(kf0, qf[ds], s0, 0, 0, 0);
      s1 = __builtin_amdgcn_mfma_f32_32x32x16_bf16(kf1, qf[ds], s1, 0, 0, 0);
    }

    // ---- softmax numerator in exp2 domain, no max subtraction
#pragma unroll
    for (int r = 0; r < 16; ++r) {
      s0[r] = fexp2(s0[r]);
      s1[r] = fexp2(s1[r]);
    }

    // ---- PV: O^T[d][q] += V^T . P ; l via ones-row MFMA into o2
    PV_STEP(s0, 0, 0)
    PV_STEP(s0, 8, 1)
    PV_STEP(s1, 0, 2)
    PV_STEP(s1, 8, 3)

    cur = (cur + 1) & 3;
  }

  const float inv = 1.f / o2[0];
  {
    const size_t row = ((size_t)b * kN + q0w + ql) * kC + h * 64;
#pragma unroll
    for (int g = 0; g < 4; ++g) {
      u32x2 pk;
      pk.x = cvtpk(o0[g * 4 + 0] * inv, o0[g * 4 + 1] * inv);
      pk.y = cvtpk(o0[g * 4 + 2] * inv, o0[g * 4 + 3] * inv);
      *reinterpret_cast<u32x2*>(&obuf[row + g * 8 + 4 * hi]) = pk;
    }
#pragma unroll
    for (int g = 0; g < 4; ++g) {
      u32x2 pk;
      pk.x = cvtpk(o1[g * 4 + 0] * inv, o1[g * 4 + 1] * inv);
      pk.y = cvtpk(o1[g * 4 + 2] * inv, o1[g * 4 + 3] * inv);
      *reinterpret_cast<u32x2*>(&obuf[row + 32 + g * 8 + 4 * hi]) = pk;
    }
  }
}

// ---------------- proj (transposed): out[b,c,n] = sum_k W2[c,k]*obuf[b,n,k] + b2[c] + tn[b,n,c] ----------------
__global__ __launch_bounds__(256) void proj_kernel(const u16* __restrict__ obuf, const u16* __restrict__ w2b,
                                                   const float* __restrict__ b2, const u16* __restrict__ tn,
                                                   float* __restrict__ out) {
  __shared__ u16 lAs[3 * 4096], lBs[3 * 4096];
  const int wg = blockIdx.x;
  const int xcd = wg & 7, idx = wg >> 3;
  const int bn = xcd * 18 + idx / 3;
  const int b = bn / 18;
  const int n0 = (bn % 18) * 128;
  const int c0 = (idx % 3) * 128;
  f32x4 acc[4][4] = {};
  gemm_core(w2b + (size_t)c0 * kC, obuf + ((size_t)b * kN + n0) * kC, acc, lAs, lBs);

  const int t = threadIdx.x, lane = t & 63, w = t >> 6;
  const int wr = w >> 1, wc = w & 1, lr = lane & 15, lg = lane >> 4;
#pragma unroll
  for (int fm = 0; fm < 4; ++fm)
#pragma unroll
    for (int fn = 0; fn < 4; ++fn) {
      int n = n0 + wc * 64 + fn * 16 + lr;
#pragma unroll
      for (int r = 0; r < 4; ++r) {
        int c = c0 + wr * 64 + fm * 16 + lg * 4 + r;
        float val = acc[fm][fn][r] + b2[c] + bf2f(tn[((size_t)b * kN + n) * kC + c]);
        out[((size_t)b * kC + c) * kN + n] = val;
      }
    }
}

extern "C" void kernel_launch(void* const* d_in, const int* in_sizes, int n_in,
                              void* d_out, int out_size, void* d_ws, size_t ws_size,
                              hipStream_t stream) {
  const float* x  = (const float*)d_in[0];
  const float* W1 = (const float*)d_in[1];
  const float* b1 = (const float*)d_in[2];
  const float* W2 = (const float*)d_in[3];
  const float* b2 = (const float*)d_in[4];
  float* out = (float*)d_out;

  const size_t nBNC = (size_t)kM * kC;  // 7,077,888 elements
  u16* tn  = (u16*)d_ws;
  u16* qb  = tn  + nBNC;
  u16* kb  = qb  + nBNC;
  u16* vb  = kb  + nBNC;   // free slot: obuf lives here
  u16* vT  = vb  + nBNC;
  u16* w1b = vT  + nBNC;
  u16* w2b = w1b + (size_t)k3C * kC;
  u16* obuf = vb;

  ln_cast_kernel<<<dim3(576 + 576), dim3(256), 0, stream>>>(x, tn, W1, W2, w1b, w2b);
  qkv_kernel<<<dim3(8 * 81), dim3(512), 0, stream>>>(tn, w1b, b1, qb, kb, vT);
  attn_kernel<<<dim3((kN / 256) * kB * kNH), dim3(512), 0, stream>>>(qb, kb, vT, obuf);
  proj_kernel<<<dim3((kN / 128) * (kC / 128) * kB), dim3(256), 0, stream>>>(obuf, w2b, b2, tn, out);
}

// Round 14
// 149.736 us; speedup vs baseline: 1.2527x; 1.0187x over previous
//
#include <hip/hip_runtime.h>
#include <cstdint>

#define DEVI __device__ __forceinline__

typedef unsigned short u16;
typedef __attribute__((ext_vector_type(4))) u16 u16x4;
typedef __attribute__((ext_vector_type(2))) unsigned int u32x2;
typedef __attribute__((ext_vector_type(2))) float f32x2;
typedef __attribute__((ext_vector_type(4))) float f32x4;
typedef __attribute__((ext_vector_type(8))) float f32x8;
typedef __attribute__((ext_vector_type(16))) float f32x16;
typedef __attribute__((ext_vector_type(8))) __bf16 bf16x8;

constexpr int kB = 8, kC = 384, kN = 2304, kNH = 6, kD = 64;
constexpr int kM = kB * kN;   // 18432
constexpr int k3C = 3 * kC;   // 1152
constexpr int kNT = kN / 64;  // 36 k-tiles (attn)
constexpr int kKS = kC / 32;  // 12 K-steps (gemm)
constexpr int kW1E = k3C * kC;  // 442368
constexpr int kW2E = kC * kC;   // 147456

DEVI float bf2f(u16 u) {
  union { unsigned int u; float f; } v; v.u = ((unsigned int)u) << 16; return v.f;
}
DEVI u16 f2bf(float f) {
  union { float f; unsigned int u; } v; v.f = f;
  return (u16)((v.u + 0x7fffu + ((v.u >> 16) & 1u)) >> 16);
}
DEVI void gload16(const void* g, void* l) {
  __builtin_amdgcn_global_load_lds(
      (__attribute__((address_space(1))) void*)const_cast<void*>(g),
      (__attribute__((address_space(3))) void*)l, 16, 0, 0);
}
DEVI bf16x8 ldg8(const u16* p) { return *reinterpret_cast<const bf16x8*>(p); }

DEVI float fexp2(float x) {
#if __has_builtin(__builtin_amdgcn_exp2f)
  return __builtin_amdgcn_exp2f(x);
#else
  return exp2f(x);
#endif
}

// pack two f32 -> one u32 of 2 bf16 (RNE), low word = first arg
DEVI unsigned cvtpk(float lo, float hi) {
  unsigned r;
  asm("v_cvt_pk_bf16_f32 %0, %1, %2" : "=v"(r) : "v"(lo), "v"(hi));
  return r;
}
// exchange halves across lane<32 / lane>=32
DEVI void plswap(unsigned& a, unsigned& b) {
#if __has_builtin(__builtin_amdgcn_permlane32_swap)
  auto rr = __builtin_amdgcn_permlane32_swap(a, b, false, false);
  a = rr[0]; b = rr[1];
#else
  unsigned ax = __shfl_xor(a, 32, 64), bx = __shfl_xor(b, 32, 64);
  int hi = (threadIdx.x & 63) >> 5;
  unsigned r0 = hi ? bx : a;
  unsigned r1 = hi ? b : ax;
  a = r0; b = r1;
#endif
}

// swizzled LDS read: tile row-major [rows][128 B], byte col XOR'd by row key
DEVI bf16x8 ldsw(const u16* base, int row, int cb) {
  return *reinterpret_cast<const bf16x8*>(
      (const char*)base + row * 128 + (cb ^ ((row & 7) << 4)));
}

// ---------------- LayerNorm + weight-cast fused ----------------
// blocks 0..575: LN over 32-row n-tiles (b = wg&7 -> batch b's tn lands on
// XCD b's L2). blocks 576..1151: cast W1/W2 to bf16, 4 elems/thread.
__global__ __launch_bounds__(256) void ln_cast_kernel(const float* __restrict__ x,
                                                      u16* __restrict__ tn,
                                                      const float* __restrict__ W1,
                                                      const float* __restrict__ W2,
                                                      u16* __restrict__ w1b,
                                                      u16* __restrict__ w2b) {
  if (blockIdx.x >= 576) {
    const int gid = (blockIdx.x - 576) * 256 + threadIdx.x;
    const int i4 = gid * 4;
    if (i4 < kW1E) {
      f32x4 v = *reinterpret_cast<const f32x4*>(&W1[i4]);
      u16x4 o;
#pragma unroll
      for (int r = 0; r < 4; ++r) o[r] = f2bf(v[r]);
      *reinterpret_cast<u16x4*>(&w1b[i4]) = o;
    } else if (i4 < kW1E + kW2E) {
      const int j = i4 - kW1E;
      f32x4 v = *reinterpret_cast<const f32x4*>(&W2[j]);
      u16x4 o;
#pragma unroll
      for (int r = 0; r < 4; ++r) o[r] = f2bf(v[r]);
      *reinterpret_cast<u16x4*>(&w2b[j]) = o;
    }
    return;
  }
  const int b = blockIdx.x & 7;
  const int n0 = (blockIdx.x >> 3) * 32;
  const int t = threadIdx.x;
  const int tni = t & 31, tc = t >> 5;  // tni: n in [0,32), tc: c-slice [0,8)
  const float* xb = x + (size_t)b * kC * kN;

  float sum = 0.f, ssq = 0.f;
  for (int c = tc; c < kC; c += 8) {
    float v = xb[(size_t)c * kN + n0 + tni];
    sum += v; ssq += v * v;
  }
  __shared__ float red[16][32];
  red[tc][tni] = sum; red[tc + 8][tni] = ssq;
  __syncthreads();
  __shared__ float s_mu[32], s_rs[32];
  if (t < 32) {
    float s = 0.f, q = 0.f;
#pragma unroll
    for (int j = 0; j < 8; ++j) { s += red[j][t]; q += red[j + 8][t]; }
    float mu = s * (1.f / kC);
    float var = q * (1.f / kC) - mu * mu;
    s_mu[t] = mu; s_rs[t] = rsqrtf(var + 1e-5f);
  }
  __syncthreads();
  __shared__ float tile[32][65];
  for (int c0 = 0; c0 < kC; c0 += 64) {
#pragma unroll
    for (int kk = 0; kk < 8; ++kk) {
      int cl = tc * 8 + kk;
      tile[tni][cl] = xb[(size_t)(c0 + cl) * kN + n0 + tni];
    }
    __syncthreads();
    const int tci = t & 63, trw = t >> 6;
#pragma unroll
    for (int kk = 0; kk < 8; ++kk) {
      int nl = trw * 8 + kk;
      float v = (tile[nl][tci] - s_mu[nl]) * s_rs[nl];
      tn[((size_t)b * kN + n0 + nl) * kC + c0 + tci] = f2bf(v);
    }
    __syncthreads();
  }
}

// ---- GEMM helpers: 64 B rows, slot key = (r>>1)&3 -> 8 rows cover 32 banks ----
DEVI int swzg(int r, int sl) { return (sl ^ ((r >> 1) & 3)) * 8; }  // u16 offset

// ================= 128x128 core (proj), 256 thr, BK=32, triple-buffer =================
#define GSTAGE(dstLds, gbase, kt)                                        \
  {                                                                      \
    _Pragma("unroll")                                                    \
    for (int c = 0; c < 2; ++c) {                                        \
      int i = c * 256 + t;                                               \
      int r = i >> 2, sl = i & 3;                                        \
      gload16((gbase) + (size_t)r * kC + (kt) + swzg(r, sl),             \
              (dstLds) + (c * 256 + (t & 192)) * 8);                     \
    }                                                                    \
  }

DEVI void gemm_core(const u16* __restrict__ A, const u16* __restrict__ Bm,
                    f32x4 acc[4][4], u16* lA, u16* lB) {
  const int t = threadIdx.x;
  const int lane = t & 63;
  const int w = t >> 6, wr = w >> 1, wc = w & 1;
  const int lr = lane & 15, lg = lane >> 4;

  GSTAGE(lA, A, 0)
  GSTAGE(lB, Bm, 0)

  int cur = 0;
#pragma unroll 3
  for (int s = 0; s < kKS; ++s) {
    const u16* cA = lA + cur * 4096;
    const u16* cB = lB + cur * 4096;
    const int nxt = (cur == 2) ? 0 : cur + 1;
    if (s + 1 < kKS) {
      GSTAGE(lA + nxt * 4096, A, (s + 1) * 32)
      GSTAGE(lB + nxt * 4096, Bm, (s + 1) * 32)
      asm volatile("s_waitcnt vmcnt(4)" ::: "memory");
    } else {
      asm volatile("s_waitcnt vmcnt(0)" ::: "memory");
    }
    __builtin_amdgcn_s_barrier();
    __builtin_amdgcn_sched_barrier(0);

    bf16x8 af[4], bfr[4];
#pragma unroll
    for (int f = 0; f < 4; ++f) {
      int row = wr * 64 + f * 16 + lr;
      af[f] = ldg8(&cA[row * 32 + swzg(row, lg)]);
    }
#pragma unroll
    for (int f = 0; f < 4; ++f) {
      int row = wc * 64 + f * 16 + lr;
      bfr[f] = ldg8(&cB[row * 32 + swzg(row, lg)]);
    }
    __builtin_amdgcn_s_setprio(1);
#pragma unroll
    for (int fm = 0; fm < 4; ++fm)
#pragma unroll
      for (int fn = 0; fn < 4; ++fn)
        acc[fm][fn] = __builtin_amdgcn_mfma_f32_16x16x32_bf16(af[fm], bfr[fn], acc[fm][fn], 0, 0, 0);
    __builtin_amdgcn_s_setprio(0);
    cur = nxt;
  }
}

// ================= 256x128 core (qkv), 512 thr / 8 waves, BK=32, triple-buffer =================
#define GSTAGE2A(dstLds, gbase, kt)                                      \
  {                                                                      \
    _Pragma("unroll")                                                    \
    for (int c = 0; c < 2; ++c) {                                        \
      int i = c * 512 + t;                                               \
      int r = i >> 2, sl = i & 3;                                        \
      gload16((gbase) + (size_t)r * kC + (kt) + swzg(r, sl),             \
              (dstLds) + (c * 512 + (t & 448)) * 8);                     \
    }                                                                    \
  }
#define GSTAGE2B(dstLds, gbase, kt)                                      \
  {                                                                      \
    int r = t >> 2, sl = t & 3;                                          \
    gload16((gbase) + (size_t)r * kC + (kt) + swzg(r, sl),               \
            (dstLds) + (t & 448) * 8);                                   \
  }

DEVI void gemm_core256(const u16* __restrict__ A, const u16* __restrict__ Bm,
                       f32x4 acc[4][4], u16* lA, u16* lB) {
  const int t = threadIdx.x;
  const int lane = t & 63;
  const int w = t >> 6, wr = w >> 1, wc = w & 1;
  const int lr = lane & 15, lg = lane >> 4;

  GSTAGE2A(lA, A, 0)
  GSTAGE2B(lB, Bm, 0)

  int cur = 0;
#pragma unroll 3
  for (int s = 0; s < kKS; ++s) {
    const u16* cA = lA + cur * 8192;
    const u16* cB = lB + cur * 4096;
    const int nxt = (cur == 2) ? 0 : cur + 1;
    if (s + 1 < kKS) {
      GSTAGE2A(lA + nxt * 8192, A, (s + 1) * 32)
      GSTAGE2B(lB + nxt * 4096, Bm, (s + 1) * 32)
      asm volatile("s_waitcnt vmcnt(3)" ::: "memory");
    } else {
      asm volatile("s_waitcnt vmcnt(0)" ::: "memory");
    }
    __builtin_amdgcn_s_barrier();
    __builtin_amdgcn_sched_barrier(0);

    bf16x8 af[4], bfr[4];
#pragma unroll
    for (int f = 0; f < 4; ++f) {
      int row = wr * 64 + f * 16 + lr;
      af[f] = ldg8(&cA[row * 32 + swzg(row, lg)]);
    }
#pragma unroll
    for (int f = 0; f < 4; ++f) {
      int row = wc * 64 + f * 16 + lr;
      bfr[f] = ldg8(&cB[row * 32 + swzg(row, lg)]);
    }
    __builtin_amdgcn_s_setprio(1);
#pragma unroll
    for (int fm = 0; fm < 4; ++fm)
#pragma unroll
      for (int fn = 0; fn < 4; ++fn)
        acc[fm][fn] = __builtin_amdgcn_mfma_f32_16x16x32_bf16(af[fm], bfr[fn], acc[fm][fn], 0, 0, 0);
    __builtin_amdgcn_s_setprio(0);
    cur = nxt;
  }
}

// ---------------- QKV GEMM: 256x128 tiles. q,k -> [B,h,N,d]; v -> TRANSPOSED [B,h,d,N] ----------------
__global__ __launch_bounds__(512) void qkv_kernel(const u16* __restrict__ tn, const u16* __restrict__ w1b,
                                                  const float* __restrict__ b1,
                                                  u16* __restrict__ q, u16* __restrict__ kbuf,
                                                  u16* __restrict__ vTout) {
  __shared__ u16 shmem[36864];  // 72KB: A bufs 3x8192, B bufs 3x4096; reused for transpose
  const int wg = blockIdx.x;
  const int xcd = wg & 7, idx = wg >> 3;
  const int m0 = (xcd * 9 + idx / 9) * 256;
  const int o0 = (idx % 9) * 128;
  f32x4 acc[4][4] = {};
  gemm_core256(tn + (size_t)m0 * kC, w1b + (size_t)o0 * kC, acc, shmem, shmem + 3 * 8192);

  const int t = threadIdx.x, lane = t & 63, w = t >> 6;
  const int wr = w >> 1, wc = w & 1, lr = lane & 15, lg = lane >> 4;
  const float kQScale = 0.125f * 1.44269504088896f;
  const int bb = xcd;
  const int nb0 = (idx / 9) * 256;
  const int ot = o0 >> 7;

  if (ot >= 6) {
    // ---- v: write transposed [b,h,d,n], 8B stores (n-fast)
#pragma unroll
    for (int fn = 0; fn < 4; ++fn) {
      int ol = o0 - 2 * kC + wc * 64 + fn * 16 + lr;
      float bias = b1[2 * kC + ol];
      int h = ol >> 6, dd = ol & 63;
#pragma unroll
      for (int fm = 0; fm < 4; ++fm) {
        int n4 = nb0 + wr * 64 + fm * 16 + lg * 4;
        u16x4 pk;
#pragma unroll
        for (int r = 0; r < 4; ++r) pk[r] = f2bf(acc[fm][fn][r] + bias);
        *reinterpret_cast<u16x4*>(&vTout[(((size_t)bb * kNH + h) * kD + dd) * kN + n4]) = pk;
      }
    }
  } else {
    // ---- q/k: LDS transpose -> coalesced 16B stores
    __syncthreads();
    const float scale = (ot < 3) ? kQScale : 1.0f;
#pragma unroll
    for (int fn = 0; fn < 4; ++fn) {
      int col = wc * 64 + fn * 16 + lr;
      float bias = b1[o0 + col];
#pragma unroll
      for (int fm = 0; fm < 4; ++fm)
#pragma unroll
        for (int r = 0; r < 4; ++r) {
          int row = wr * 64 + fm * 16 + lg * 4 + r;
          shmem[row * 132 + col] = f2bf((acc[fm][fn][r] + bias) * scale);
        }
    }
    __syncthreads();
    u16* outp = (ot < 3) ? q : kbuf;
    const int h0 = (o0 - (ot < 3 ? 0 : kC)) >> 6;
#pragma unroll
    for (int it = 0; it < 8; ++it) {
      int ci = it * 512 + t;
      int row = ci >> 4, ck = ci & 15;
      int c = ck * 8;
      int h = h0 + (c >> 6), dd = c & 63;
      *reinterpret_cast<bf16x8*>(&outp[(((size_t)bb * kNH + h) * kN + nb0 + row) * kD + dd]) =
          *reinterpret_cast<const bf16x8*>(&shmem[row * 132 + c]);
    }
  }
}

// ---------------- flash attention v14: 8 waves, depth-2 prefetch; l-sum on VALU ----------------
// 432 blocks = 8 XCD x (6 heads x 9 q-tiles), 512 thr / 8 waves x 32 q-rows.
// Stage tile t+2 at iter t; counted s_waitcnt vmcnt(4)/(2)/(0) never drains
// mid-loop. exp2-domain softmax, no max tracking. l-sum via packed vector
// adds + end-of-loop tree (MFMA is the busier pipe: ones-MFMA removed cuts
// the binding pipe by 20%).
#define PV_STEP(SV, OFF, KS)                                                          \
  {                                                                                   \
    unsigned a0 = cvtpk(SV[OFF + 0], SV[OFF + 1]);                                    \
    unsigned a1 = cvtpk(SV[OFF + 2], SV[OFF + 3]);                                    \
    unsigned a2 = cvtpk(SV[OFF + 4], SV[OFF + 5]);                                    \
    unsigned a3 = cvtpk(SV[OFF + 6], SV[OFF + 7]);                                    \
    plswap(a0, a2); plswap(a1, a3);                                                   \
    union { unsigned wds[4]; bf16x8 v; } pu;                                          \
    pu.wds[0] = a0; pu.wds[1] = a1; pu.wds[2] = a2; pu.wds[3] = a3;                   \
    bf16x8 vf0 = ldsw(vL, ql, (KS) * 32 + hi * 16);                                   \
    bf16x8 vf1 = ldsw(vL, 32 + ql, (KS) * 32 + hi * 16);                              \
    o0 = __builtin_amdgcn_mfma_f32_32x32x16_bf16(vf0, pu.v, o0, 0, 0, 0);             \
    o1 = __builtin_amdgcn_mfma_f32_32x32x16_bf16(vf1, pu.v, o1, 0, 0, 0);             \
  }

// stage one 64-row tile (row stride `gstride` bytes); 512 threads = 1 load each
#define STAGE(dstLds, gbase, gstride)                                                 \
  {                                                                                   \
    int r_ = t >> 3;                                                                  \
    int cb_ = ((t & 7) * 16) ^ ((r_ & 7) << 4);                                       \
    gload16((gbase) + (size_t)r_ * (gstride) + cb_,                                   \
            (dstLds) + (t & 448) * 8);                                                \
  }

__global__ __launch_bounds__(512) void attn_kernel(const u16* __restrict__ qg, const u16* __restrict__ kg,
                                                   const u16* __restrict__ vT, u16* __restrict__ obuf) {
  const int wg = blockIdx.x;
  const int xcd = wg & 7, idx = wg >> 3;
  const int bh = xcd * 6 + idx / 9;
  const int qt = idx % 9;
  const int b = bh / kNH, h = bh % kNH;
  const int t = threadIdx.x, lane = t & 63, w = t >> 6;
  const int q0w = qt * 256 + w * 32;
  const int ql = lane & 31;
  const int hi = lane >> 5;
  const u16* qb  = qg + (size_t)bh * kN * kD;
  const char* kbB = (const char*)(kg + (size_t)bh * kN * kD);
  const char* vbT = (const char*)(vT + (size_t)bh * kD * kN);

  __shared__ u16 kLds[4 * 4096];
  __shared__ u16 vLds[4 * 4096];

  // Q as B-fragment: Q[q0w+ql][ds*16 + hi*8 + j]
  bf16x8 qf[4];
#pragma unroll
  for (int ds = 0; ds < 4; ++ds)
    qf[ds] = ldg8(&qb[(size_t)(q0w + ql) * kD + ds * 16 + hi * 8]);

  f32x16 o0 = {}, o1 = {};
  f32x16 lsum = {};

  // depth-2 prologue: tiles 0 and 1
  STAGE(kLds, kbB, 128)
  STAGE(vLds, vbT, kN * 2)
  STAGE(kLds + 4096, kbB + (size_t)64 * 128, 128)
  STAGE(vLds + 4096, vbT + 128, kN * 2)

  int cur = 0;
  for (int ti = 0; ti < kNT; ++ti) {
    const u16* kL = kLds + cur * 4096;
    const u16* vL = vLds + cur * 4096;
    if (ti + 2 < kNT) {
      const int stg = (cur + 2) & 3;
      const char* kNext = kbB + (size_t)(ti + 2) * 64 * 128;
      const char* vNext = vbT + (size_t)(ti + 2) * 128;
      STAGE(kLds + stg * 4096, kNext, 128)
      STAGE(vLds + stg * 4096, vNext, kN * 2)
      asm volatile("s_waitcnt vmcnt(4)" ::: "memory");
    } else if (ti + 1 < kNT) {
      asm volatile("s_waitcnt vmcnt(2)" ::: "memory");
    } else {
      asm volatile("s_waitcnt vmcnt(0)" ::: "memory");
    }
    __builtin_amdgcn_s_barrier();
    __builtin_amdgcn_sched_barrier(0);

    // ---- S^T[k][q] = K . Q^T : s0 = k-rows [0,32), s1 = [32,64) of tile
    f32x16 s0 = {}, s1 = {};
#pragma unroll
    for (int ds = 0; ds < 4; ++ds) {
      bf16x8 kf0 = ldsw(kL, ql, ds * 32 + hi * 16);
      bf16x8 kf1 = ldsw(kL, 32 + ql, ds * 32 + hi * 16);
      s0 = __builtin_amdgcn_mfma_f32_32x32x16_bf16(kf0, qf[ds], s0, 0, 0, 0);
      s1 = __builtin_amdgcn_mfma_f32_32x32x16_bf16(kf1, qf[ds], s1, 0, 0, 0);
    }

    // ---- softmax numerator in exp2 domain, no max subtraction
#pragma unroll
    for (int r = 0; r < 16; ++r) {
      s0[r] = fexp2(s0[r]);
      s1[r] = fexp2(s1[r]);
    }
    lsum += s0;
    lsum += s1;

    // ---- PV: O^T[d][q] += V^T . P ; P fragments built in-register
    PV_STEP(s0, 0, 0)
    PV_STEP(s0, 8, 1)
    PV_STEP(s1, 0, 2)
    PV_STEP(s1, 8, 3)

    cur = (cur + 1) & 3;
  }

  // horizontal reduce of lsum (16 regs) + cross-half add
  f32x8 r8 = __builtin_shufflevector(lsum, lsum, 0, 1, 2, 3, 4, 5, 6, 7) +
             __builtin_shufflevector(lsum, lsum, 8, 9, 10, 11, 12, 13, 14, 15);
  f32x4 r4 = __builtin_shufflevector(r8, r8, 0, 1, 2, 3) +
             __builtin_shufflevector(r8, r8, 4, 5, 6, 7);
  f32x2 r2 = __builtin_shufflevector(r4, r4, 0, 1) +
             __builtin_shufflevector(r4, r4, 2, 3);
  float l = r2.x + r2.y;
  l += __shfl_xor(l, 32, 64);

  const float inv = 1.f / l;
  {
    const size_t row = ((size_t)b * kN + q0w + ql) * kC + h * 64;
#pragma unroll
    for (int g = 0; g < 4; ++g) {
      u32x2 pk;
      pk.x = cvtpk(o0[g * 4 + 0] * inv, o0[g * 4 + 1] * inv);
      pk.y = cvtpk(o0[g * 4 + 2] * inv, o0[g * 4 + 3] * inv);
      *reinterpret_cast<u32x2*>(&obuf[row + g * 8 + 4 * hi]) = pk;
    }
#pragma unroll
    for (int g = 0; g < 4; ++g) {
      u32x2 pk;
      pk.x = cvtpk(o1[g * 4 + 0] * inv, o1[g * 4 + 1] * inv);
      pk.y = cvtpk(o1[g * 4 + 2] * inv, o1[g * 4 + 3] * inv);
      *reinterpret_cast<u32x2*>(&obuf[row + 32 + g * 8 + 4 * hi]) = pk;
    }
  }
}

// ---------------- proj (transposed): out[b,c,n] = sum_k W2[c,k]*obuf[b,n,k] + b2[c] + tn[b,n,c] ----------------
__global__ __launch_bounds__(256) void proj_kernel(const u16* __restrict__ obuf, const u16* __restrict__ w2b,
                                                   const float* __restrict__ b2, const u16* __restrict__ tn,
                                                   float* __restrict__ out) {
  __shared__ u16 lAs[3 * 4096], lBs[3 * 4096];
  const int wg = blockIdx.x;
  const int xcd = wg & 7, idx = wg >> 3;
  const int bn = xcd * 18 + idx / 3;
  const int b = bn / 18;
  const int n0 = (bn % 18) * 128;
  const int c0 = (idx % 3) * 128;
  f32x4 acc[4][4] = {};
  gemm_core(w2b + (size_t)c0 * kC, obuf + ((size_t)b * kN + n0) * kC, acc, lAs, lBs);

  const int t = threadIdx.x, lane = t & 63, w = t >> 6;
  const int wr = w >> 1, wc = w & 1, lr = lane & 15, lg = lane >> 4;
#pragma unroll
  for (int fm = 0; fm < 4; ++fm)
#pragma unroll
    for (int fn = 0; fn < 4; ++fn) {
      int n = n0 + wc * 64 + fn * 16 + lr;
#pragma unroll
      for (int r = 0; r < 4; ++r) {
        int c = c0 + wr * 64 + fm * 16 + lg * 4 + r;
        float val = acc[fm][fn][r] + b2[c] + bf2f(tn[((size_t)b * kN + n) * kC + c]);
        out[((size_t)b * kC + c) * kN + n] = val;
      }
    }
}

extern "C" void kernel_launch(void* const* d_in, const int* in_sizes, int n_in,
                              void* d_out, int out_size, void* d_ws, size_t ws_size,
                              hipStream_t stream) {
  const float* x  = (const float*)d_in[0];
  const float* W1 = (const float*)d_in[1];
  const float* b1 = (const float*)d_in[2];
  const float* W2 = (const float*)d_in[3];
  const float* b2 = (const float*)d_in[4];
  float* out = (float*)d_out;

  const size_t nBNC = (size_t)kM * kC;  // 7,077,888 elements
  u16* tn  = (u16*)d_ws;
  u16* qb  = tn  + nBNC;
  u16* kb  = qb  + nBNC;
  u16* vb  = kb  + nBNC;   // free slot: obuf lives here
  u16* vT  = vb  + nBNC;
  u16* w1b = vT  + nBNC;
  u16* w2b = w1b + (size_t)k3C * kC;
  u16* obuf = vb;

  ln_cast_kernel<<<dim3(576 + 576), dim3(256), 0, stream>>>(x, tn, W1, W2, w1b, w2b);
  qkv_kernel<<<dim3(8 * 81), dim3(512), 0, stream>>>(tn, w1b, b1, qb, kb, vT);
  attn_kernel<<<dim3((kN / 256) * kB * kNH), dim3(512), 0, stream>>>(qb, kb, vT, obuf);
  proj_kernel<<<dim3((kN / 128) * (kC / 128) * kB), dim3(256), 0, stream>>>(obuf, w2b, b2, tn, out);
}